// Round 4
// baseline (3225.175 us; speedup 1.0000x reference)
//
#include <hip/hip_runtime.h>
#include <hip/hip_bf16.h>

#define HH 51
#define TPB 512     // 8 waves, 1 block/CU. Waves 0-2: Whh1 tiles + e1. Waves 3-7: Whh2/Wih2 pairs + e2 + out.
#define BPB 8

typedef _Float16 half8 __attribute__((ext_vector_type(8)));
typedef float f4 __attribute__((ext_vector_type(4)));

__device__ __forceinline__ float bf2f(unsigned short u) {
    return __uint_as_float(((unsigned)u) << 16);
}
__device__ __forceinline__ float loadf(const void* p, size_t i, bool bf) {
    return bf ? bf2f(((const unsigned short*)p)[i]) : ((const float*)p)[i];
}
__device__ __forceinline__ void storef(void* p, size_t i, float v, bool bf) {
    if (bf) ((__hip_bfloat16*)p)[i] = __float2bfloat16(v);
    else    ((float*)p)[i] = v;
}
__device__ __forceinline__ float sigm(float v) {
    float e = __expf(-fabsf(v));
    float s = 1.0f / (1.0f + e);
    return (v >= 0.0f) ? s : 1.0f - s;
}
__device__ __forceinline__ float tanh_fast(float v) {
    float e = __expf(-2.0f * fabsf(v));
    float t = (1.0f - e) / (1.0f + e);
    return (v >= 0.0f) ? t : -t;
}
__device__ __forceinline__ f4 MF(half8 a, half8 b, f4 c) {
    return __builtin_amdgcn_mfma_f32_16x16x32_f16(a, b, c, 0, 0, 0);
}
// sum over 8-stride lane classes; lane L ends with sum of {L&7, (L&7)+8, ...}
__device__ __forceinline__ float sum8cls(float v) {
    v += __shfl_xor(v, 8);
    v += __shfl_xor(v, 16);
    v += __shfl_xor(v, 32);
    return v;
}

__global__ __launch_bounds__(TPB, 2) void gru_kernel(
    const void* __restrict__ xg,
    const void* __restrict__ wih1, const void* __restrict__ whh1,
    const void* __restrict__ bih1, const void* __restrict__ bhh1,
    const void* __restrict__ wih2, const void* __restrict__ whh2,
    const void* __restrict__ bih2, const void* __restrict__ bhh2,
    const void* __restrict__ wlin, const void* __restrict__ blin_p,
    void* __restrict__ dout, int T, int TF)
{
    // W rows 4-interleaved: staged row r = 4*neuron + gate (gate 0=r,1=z,2=n,3=pad), 208 rows = 13 tiles
    __shared__ __align__(16) _Float16 stg[208 * 64];     // 26624 B, reused per matrix
    __shared__ __align__(16) _Float16 h1T[2][16 * 72];   // double-buffered h state, [batch][k], k52 = 1 (bias)
    __shared__ __align__(16) _Float16 h2T[2][16 * 72];
    __shared__ float xls[2][64 * 9];                     // x window [t&63][batch]
    __shared__ float opart[2][64];                       // out partials [wv*8 + b]
    __shared__ float opartX[64];                         // transition-phase partials
    __shared__ float obufL[8 * 68];                      // out ring, 64 entries per batch

    const int tid = threadIdx.x, w = tid >> 6, lane = tid & 63;
    const int n16 = lane & 15, q = lane >> 4;
    const int bg0 = blockIdx.x * BPB;
    const int myb = bg0 + w;

    bool isbf;
    {
        const unsigned short* u = (const unsigned short*)whh1;
        int ok = 1;
#pragma unroll
        for (int k = 0; k < 16; ++k) {
            unsigned e = (u[2 * k] >> 7) & 0xFF;
            ok &= (e >= 100 && e <= 125) ? 1 : 0;
        }
        isbf = (ok != 0);
    }

    const bool isA = (w < 3);
    int tbase, tcnt;
    if (isA) { tbase = (w == 0) ? 0 : (w == 1) ? 5 : 9; tcnt = (w == 0) ? 5 : 4; }
    else {
        int i = w - 3;
        tbase = (i == 0) ? 0 : (i == 1) ? 3 : (i == 2) ? 6 : (i == 3) ? 9 : 11;
        tcnt = (i < 3) ? 3 : 2;
    }

    half8 WA[5][2], WH[3][2], WI[3][2];

    // ---- stage matrices (f16, 4-interleaved rows, biases folded at k=52) ----
#pragma unroll 1
    for (int mt = 0; mt < 3; ++mt) {
        const void* wm = (mt == 0) ? whh1 : (mt == 1) ? whh2 : wih2;
        for (int e = tid; e < 208 * 64; e += TPB) {
            int r = e >> 6, k = e & 63;
            int nn = r >> 2, g8 = r & 3;
            float v = 0.0f;
            if (nn < HH && g8 < 3) {
                int g = g8 * HH + nn;
                if (k < HH) v = loadf(wm, (size_t)g * HH + k, isbf);
                else if (k == 52) {
                    if (mt == 0)      v = loadf(bhh1, g, isbf) + ((g8 < 2) ? loadf(bih1, g, isbf) : 0.0f);
                    else if (mt == 1) v = loadf(bhh2, g, isbf);
                    else              v = loadf(bih2, g, isbf);
                }
            }
            stg[e] = (_Float16)v;
        }
        __syncthreads();
        if (mt == 0 && isA) {
#pragma unroll
            for (int s = 0; s < 5; ++s) if (s < tcnt) {
                int tl = tbase + s;
                WA[s][0] = *(const half8*)(stg + (size_t)(16 * tl + n16) * 64 + q * 8);
                WA[s][1] = *(const half8*)(stg + (size_t)(16 * tl + n16) * 64 + 32 + q * 8);
            }
        } else if (mt == 1 && !isA) {
#pragma unroll
            for (int s = 0; s < 3; ++s) if (s < tcnt) {
                int tl = tbase + s;
                WH[s][0] = *(const half8*)(stg + (size_t)(16 * tl + n16) * 64 + q * 8);
                WH[s][1] = *(const half8*)(stg + (size_t)(16 * tl + n16) * 64 + 32 + q * 8);
            }
        } else if (mt == 2 && !isA) {
#pragma unroll
            for (int s = 0; s < 3; ++s) if (s < tcnt) {
                int tl = tbase + s;
                WI[s][0] = *(const half8*)(stg + (size_t)(16 * tl + n16) * 64 + q * 8);
                WI[s][1] = *(const half8*)(stg + (size_t)(16 * tl + n16) * 64 + 32 + q * 8);
            }
        }
        __syncthreads();
    }

    // ---- init LDS state ----
    for (int e = tid; e < 16 * 72; e += TPB) {
        h1T[0][e] = (_Float16)0; h1T[1][e] = (_Float16)0;
        h2T[0][e] = (_Float16)0; h2T[1][e] = (_Float16)0;
    }
    if (tid < 128) opart[tid >> 6][tid & 63] = 0.0f;
    if (tid < 64)  opartX[tid] = 0.0f;

    // per-lane constants: A-waves get wih1/bih1 for neuron u = 4*tl + q; B-waves get wlin
    float r1c[5], z1c[5], n1c[5], bnc[5], wlc[3];
#pragma unroll
    for (int s = 0; s < 5; ++s) { r1c[s] = z1c[s] = n1c[s] = bnc[s] = 0.0f; }
    wlc[0] = wlc[1] = wlc[2] = 0.0f;
    if (isA) {
#pragma unroll
        for (int s = 0; s < 5; ++s) if (s < tcnt) {
            int u = 4 * (tbase + s) + q;
            if (u < HH) {
                r1c[s] = loadf(wih1, u, isbf);
                z1c[s] = loadf(wih1, HH + u, isbf);
                n1c[s] = loadf(wih1, 2 * HH + u, isbf);
                bnc[s] = loadf(bih1, 2 * HH + u, isbf);
            }
        }
    } else {
#pragma unroll
        for (int s = 0; s < 3; ++s) if (s < tcnt) {
            int u = 4 * (tbase + s) + q;
            if (u < HH) wlc[s] = loadf(wlin, u, isbf);
        }
    }
    const float blv = loadf(blin_p, 0, isbf);

    float xr = 0.0f;
    if (lane < T) xr = loadf(xg, (size_t)myb * T + lane, isbf);
    __syncthreads();
    if (tid < 16) {   // bias slot k=52 = 1.0 in both buffers
        h1T[0][tid * 72 + 52] = (_Float16)1.0f; h1T[1][tid * 72 + 52] = (_Float16)1.0f;
        h2T[0][tid * 72 + 52] = (_Float16)1.0f; h2T[1][tid * 72 + 52] = (_Float16)1.0f;
    }
    xls[0][lane * 9 + w] = xr;   // window 0
    __syncthreads();

    float h1s[5] = {0, 0, 0, 0, 0};
    float h2s[3] = {0, 0, 0};

    // ================= encode: ONE barrier per step =================
    // phase p: A computes e1(p) [reads h1(p-1)], B computes e2(p-1) [reads h1(p-1), h2(p-2)]
    for (int p = 0; p < T; ++p) {
        const int rb = (p - 1) & 1, wb = p & 1;
        if (isA) {
            const _Float16* hp = h1T[rb];
            half8 H0 = *(const half8*)(hp + n16 * 72 + q * 8);
            half8 H1 = *(const half8*)(hp + n16 * 72 + 32 + q * 8);
            float xv = xls[(p >> 6) & 1][(p & 63) * 9 + (n16 & 7)];
            _Float16* hw = h1T[wb];
#pragma unroll
            for (int s = 0; s < 5; ++s) if (s < tcnt) {
                f4 acc = {0.f, 0.f, 0.f, 0.f};
                acc = MF(WA[s][0], H0, acc); acc = MF(WA[s][1], H1, acc);
                float rr = sigm(fmaf(xv, r1c[s], acc[0]));
                float zz = sigm(fmaf(xv, z1c[s], acc[1]));
                float nn = tanh_fast(fmaf(xv, n1c[s], bnc[s]) + rr * acc[2]);
                float h = nn + zz * (h1s[s] - nn); h1s[s] = h;
                int u = 4 * (tbase + s) + q;
                if (n16 < 8 && u < HH) hw[n16 * 72 + u] = (_Float16)h;
            }
            if (w == 2 && p >= 2) {   // out(p-2) -> obuf
                float v = opart[(p - 1) & 1][lane];
                v = sum8cls(v);
                if (lane < 8) obufL[lane * 68 + ((p - 2) & 63)] = v + blv;
            }
        } else {
            const _Float16* hp1 = h1T[rb];
            const _Float16* hp2 = h2T[rb];
            half8 G0 = *(const half8*)(hp1 + n16 * 72 + q * 8);
            half8 G1 = *(const half8*)(hp1 + n16 * 72 + 32 + q * 8);
            half8 F0 = *(const half8*)(hp2 + n16 * 72 + q * 8);
            half8 F1 = *(const half8*)(hp2 + n16 * 72 + 32 + q * 8);
            _Float16* hw = h2T[wb];
            float po = 0.0f;
#pragma unroll
            for (int s = 0; s < 3; ++s) if (s < tcnt) {
                f4 aH = {0.f, 0.f, 0.f, 0.f}, aI = {0.f, 0.f, 0.f, 0.f};
                aH = MF(WH[s][0], F0, aH); aH = MF(WH[s][1], F1, aH);
                aI = MF(WI[s][0], G0, aI); aI = MF(WI[s][1], G1, aI);
                if (p >= 1) {
                    float r2 = sigm(aI[0] + aH[0]);
                    float z2 = sigm(aI[1] + aH[1]);
                    float n2 = tanh_fast(aI[2] + r2 * aH[2]);
                    float h = n2 + z2 * (h2s[s] - n2); h2s[s] = h;
                    int u = 4 * (tbase + s) + q;
                    if (n16 < 8 && u < HH) hw[n16 * 72 + u] = (_Float16)h;
                    po += h * wlc[s];
                }
            }
            if (p >= 1) {
                po += __shfl_xor(po, 16);
                po += __shfl_xor(po, 32);
                if (lane < 8) opart[wb][(w - 3) * 8 + lane] = po;
            }
            if (w == 7 && (p & 31) == 2 && p >= 34) {   // flush [p-34 .. p-3]
                int fb = p - 34;
#pragma unroll
                for (int k2 = 0; k2 < 4; ++k2) {
                    int et = k2 * 64 + lane;
                    int b = et >> 5, tt = et & 31;
                    storef(dout, (size_t)(bg0 + b) * TF + fb + tt, obufL[b * 68 + ((fb + tt) & 63)], isbf);
                }
            }
        }
        // x window refill: load at p%64==0 (for window p+64), LDS-write at p%64==32
        if ((p & 63) == 0) {
            int base = p + 64;
            if (base < T) {
                int src = base + lane;
                xr = (src < T) ? loadf(xg, (size_t)myb * T + src, isbf) : 0.0f;
            }
        } else if ((p & 63) == 32) {
            if (p + 32 < T) xls[((p >> 6) + 1) & 1][lane * 9 + w] = xr;
        }
        __syncthreads();
    }

    // ================= transition: e2(T-1) =================
    {
        const int rbT = (T - 1) & 1;
        if (!isA) {
            const _Float16* hp1 = h1T[rbT];
            const _Float16* hp2 = h2T[rbT];
            half8 G0 = *(const half8*)(hp1 + n16 * 72 + q * 8);
            half8 G1 = *(const half8*)(hp1 + n16 * 72 + 32 + q * 8);
            half8 F0 = *(const half8*)(hp2 + n16 * 72 + q * 8);
            half8 F1 = *(const half8*)(hp2 + n16 * 72 + 32 + q * 8);
            _Float16* hw = h2T[T & 1];
            float po = 0.0f;
#pragma unroll
            for (int s = 0; s < 3; ++s) if (s < tcnt) {
                f4 aH = {0.f, 0.f, 0.f, 0.f}, aI = {0.f, 0.f, 0.f, 0.f};
                aH = MF(WH[s][0], F0, aH); aH = MF(WH[s][1], F1, aH);
                aI = MF(WI[s][0], G0, aI); aI = MF(WI[s][1], G1, aI);
                float r2 = sigm(aI[0] + aH[0]);
                float z2 = sigm(aI[1] + aH[1]);
                float n2 = tanh_fast(aI[2] + r2 * aH[2]);
                float h = n2 + z2 * (h2s[s] - n2); h2s[s] = h;
                int u = 4 * (tbase + s) + q;
                if (n16 < 8 && u < HH) hw[n16 * 72 + u] = (_Float16)h;
                po += h * wlc[s];
            }
            po += __shfl_xor(po, 16);
            po += __shfl_xor(po, 32);
            if (lane < 8) opartX[(w - 3) * 8 + lane] = po;
        } else if (w == 2) {   // out(T-2)
            float v = opart[(T - 1) & 1][lane];
            v = sum8cls(v);
            if (lane < 8) obufL[lane * 68 + ((T - 2) & 63)] = v + blv;
        }
        __syncthreads();
    }

    // ================= feedback: 2 phases per step =================
    for (int t = T; t < TF; ++t) {
        // ---- A phase: e1(t) with xv = out(t-1) ----
        if (isA) {
            float v = (t == T) ? opartX[lane] : opart[(t - 1) & 1][lane];
            v = sum8cls(v);
            float xv = v + blv;
            if (w == 2 && lane < 8) obufL[lane * 68 + ((t - 1) & 63)] = xv;
            const _Float16* hp = h1T[(t - 1) & 1];
            half8 H0 = *(const half8*)(hp + n16 * 72 + q * 8);
            half8 H1 = *(const half8*)(hp + n16 * 72 + 32 + q * 8);
            _Float16* hw = h1T[t & 1];
#pragma unroll
            for (int s = 0; s < 5; ++s) if (s < tcnt) {
                f4 acc = {0.f, 0.f, 0.f, 0.f};
                acc = MF(WA[s][0], H0, acc); acc = MF(WA[s][1], H1, acc);
                float rr = sigm(fmaf(xv, r1c[s], acc[0]));
                float zz = sigm(fmaf(xv, z1c[s], acc[1]));
                float nn = tanh_fast(fmaf(xv, n1c[s], bnc[s]) + rr * acc[2]);
                float h = nn + zz * (h1s[s] - nn); h1s[s] = h;
                int u = 4 * (tbase + s) + q;
                if (n16 < 8 && u < HH) hw[n16 * 72 + u] = (_Float16)h;
            }
        } else if (w == 7 && (t & 31) == 1 && t >= 33) {   // flush [t-33 .. t-2]
            int fb = t - 33;
#pragma unroll
            for (int k2 = 0; k2 < 4; ++k2) {
                int et = k2 * 64 + lane;
                int b = et >> 5, tt = et & 31;
                storef(dout, (size_t)(bg0 + b) * TF + fb + tt, obufL[b * 68 + ((fb + tt) & 63)], isbf);
            }
        }
        __syncthreads();
        // ---- B phase: e2(t) ----
        if (!isA) {
            const _Float16* hp1 = h1T[t & 1];          // h1(t)
            const _Float16* hp2 = h2T[t & 1];          // h2(t-1)
            half8 G0 = *(const half8*)(hp1 + n16 * 72 + q * 8);
            half8 G1 = *(const half8*)(hp1 + n16 * 72 + 32 + q * 8);
            half8 F0 = *(const half8*)(hp2 + n16 * 72 + q * 8);
            half8 F1 = *(const half8*)(hp2 + n16 * 72 + 32 + q * 8);
            _Float16* hw = h2T[(t + 1) & 1];
            float po = 0.0f;
#pragma unroll
            for (int s = 0; s < 3; ++s) if (s < tcnt) {
                f4 aH = {0.f, 0.f, 0.f, 0.f}, aI = {0.f, 0.f, 0.f, 0.f};
                aH = MF(WH[s][0], F0, aH); aH = MF(WH[s][1], F1, aH);
                aI = MF(WI[s][0], G0, aI); aI = MF(WI[s][1], G1, aI);
                float r2 = sigm(aI[0] + aH[0]);
                float z2 = sigm(aI[1] + aH[1]);
                float n2 = tanh_fast(aI[2] + r2 * aH[2]);
                float h = n2 + z2 * (h2s[s] - n2); h2s[s] = h;
                int u = 4 * (tbase + s) + q;
                if (n16 < 8 && u < HH) hw[n16 * 72 + u] = (_Float16)h;
                po += h * wlc[s];
            }
            po += __shfl_xor(po, 16);
            po += __shfl_xor(po, 32);
            if (lane < 8) opart[t & 1][(w - 3) * 8 + lane] = po;
        }
        __syncthreads();
    }

    // ================= epilogue: out(TF-1) + tail flush =================
    {
        float v = opart[(TF - 1) & 1][lane];
        v = sum8cls(v);
        if (w == 2 && lane < 8) obufL[lane * 68 + ((TF - 1) & 63)] = v + blv;
    }
    __syncthreads();
    {
        int tailStart = ((TF - 34) & ~31) + 32;
        if (tid < 256) {
            int b = tid >> 5, tt = tid & 31;
            int s = tailStart + tt;
            if (s < TF) storef(dout, (size_t)(bg0 + b) * TF + s, obufL[b * 68 + (s & 63)], isbf);
        }
    }
}

extern "C" void kernel_launch(void* const* d_in, const int* in_sizes, int n_in,
                              void* d_out, int out_size, void* d_ws, size_t ws_size,
                              hipStream_t stream) {
    const int B = 2048;
    const int T = in_sizes[0] / B;   // 1000
    const int TF = out_size / B;     // 2000
    gru_kernel<<<dim3(B / BPB), dim3(TPB), 0, stream>>>(
        d_in[0], d_in[1], d_in[2], d_in[3], d_in[4], d_in[5],
        d_in[6], d_in[7], d_in[8], d_in[9], d_in[10],
        d_out, T, TF);
}

// Round 5
// 2022.542 us; speedup vs baseline: 1.5946x; 1.5946x over previous
//
#include <hip/hip_runtime.h>
#include <hip/hip_bf16.h>

#define HH 51
#define TPB 512     // 8 waves; 1 block/CU. P1: wave=batch; P2: waves 0-4 h1-jobs, waves 5-7 h2-jobs
#define BPB 8
#define GMS 9       // gbuf row stride (floats): <=2-way banks

typedef _Float16 half8 __attribute__((ext_vector_type(8)));
typedef float f4 __attribute__((ext_vector_type(4)));

// Light barrier: drain LDS only (no vmcnt/expcnt) then hw barrier.
// Global stores (dout flush) and register-dest loads (x prefetch) stay in flight.
#define LBAR() asm volatile("s_waitcnt lgkmcnt(0)\ns_barrier" ::: "memory")

__device__ __forceinline__ float bf2f(unsigned short u) {
    return __uint_as_float(((unsigned)u) << 16);
}
__device__ __forceinline__ float loadf(const void* p, size_t i, bool bf) {
    return bf ? bf2f(((const unsigned short*)p)[i]) : ((const float*)p)[i];
}
__device__ __forceinline__ void storef(void* p, size_t i, float v, bool bf) {
    if (bf) ((__hip_bfloat16*)p)[i] = __float2bfloat16(v);
    else    ((float*)p)[i] = v;
}
__device__ __forceinline__ float sigm(float v) {
    float e = __expf(-fabsf(v));
    float s = 1.0f / (1.0f + e);
    return (v >= 0.0f) ? s : 1.0f - s;
}
__device__ __forceinline__ float tanh_fast(float v) {
    float e = __expf(-2.0f * fabsf(v));
    float t = (1.0f - e) / (1.0f + e);
    return (v >= 0.0f) ? t : -t;
}
__device__ __forceinline__ f4 MF(half8 a, half8 b, f4 c) {
    return __builtin_amdgcn_mfma_f32_16x16x32_f16(a, b, c, 0, 0, 0);
}
// wave64 sum via DPP (verified rounds 5-13), result uniform across lanes
__device__ __forceinline__ float wave_sum(float x) {
    float s = x, t;
    t = __builtin_bit_cast(float, __builtin_amdgcn_update_dpp(0, __builtin_bit_cast(int, s), 0x111, 0xf, 0xf, true)); s += t;
    t = __builtin_bit_cast(float, __builtin_amdgcn_update_dpp(0, __builtin_bit_cast(int, s), 0x112, 0xf, 0xf, true)); s += t;
    t = __builtin_bit_cast(float, __builtin_amdgcn_update_dpp(0, __builtin_bit_cast(int, s), 0x114, 0xf, 0xf, true)); s += t;
    t = __builtin_bit_cast(float, __builtin_amdgcn_update_dpp(0, __builtin_bit_cast(int, s), 0x118, 0xf, 0xf, true)); s += t;
    t = __builtin_bit_cast(float, __builtin_amdgcn_update_dpp(0, __builtin_bit_cast(int, s), 0x142, 0xa, 0xf, true)); s += t;
    t = __builtin_bit_cast(float, __builtin_amdgcn_update_dpp(0, __builtin_bit_cast(int, s), 0x143, 0xc, 0xf, true)); s += t;
    return __builtin_bit_cast(float, __builtin_amdgcn_readlane(__builtin_bit_cast(int, s), 63));
}

__global__ __launch_bounds__(TPB, 2) void gru_kernel(
    const void* __restrict__ xg,
    const void* __restrict__ wih1, const void* __restrict__ whh1,
    const void* __restrict__ bih1, const void* __restrict__ bhh1,
    const void* __restrict__ wih2, const void* __restrict__ whh2,
    const void* __restrict__ bih2, const void* __restrict__ bhh2,
    const void* __restrict__ wlin, const void* __restrict__ blin_p,
    void* __restrict__ dout, int T, int TF)
{
    __shared__ __align__(16) _Float16 stg[160 * 64];        // 20480 B
    __shared__ __align__(16) float    gbuf[3 * 160 * GMS];  // 17280 B
    __shared__ __align__(16) _Float16 h1b[16 * 72];         // f16 state
    __shared__ __align__(16) _Float16 h2b[16 * 72];
    __shared__ float obufL[BPB * 36];

    const int tid = threadIdx.x, w = tid >> 6, lane = tid & 63;
    const int n16 = lane & 15, quad = lane >> 4;
    const bool li = lane < HH;
    const int il = li ? lane : HH - 1;
    const int bg0 = blockIdx.x * BPB;
    const int myb = bg0 + w;         // each of the 8 waves owns one batch

    // runtime dtype detection (fp32 vs bf16), uniform
    bool isbf;
    {
        const unsigned short* u = (const unsigned short*)whh1;
        int ok = 1;
#pragma unroll
        for (int k = 0; k < 16; ++k) {
            unsigned e = (u[2 * k] >> 7) & 0xFF;
            ok &= (e >= 100 && e <= 125) ? 1 : 0;
        }
        isbf = (ok != 0);
    }

    // elementwise constants (lane = hidden unit) -- needed before staging (blv folds into row 153)
    float wr1 = 0, wz1 = 0, wn1 = 0, bn1 = 0, wl = 0;
    if (li) {
        wr1 = loadf(wih1, il, isbf);          wz1 = loadf(wih1, HH + il, isbf);
        wn1 = loadf(wih1, 2 * HH + il, isbf); bn1 = loadf(bih1, 2 * HH + il, isbf);
        wl  = loadf(wlin, il, isbf);
    }
    const float blv = loadf(blin_p, 0, isbf);

    // ---- job table: 30 tile-jobs. h1-jobs j=0..19 (mt0 tl0-9, mt2 tl0-9) -> waves 0-4 (4 each);
    //      h2-jobs j=20..29 (mt1 tl0-9) -> waves 5 (4), 6 (3), 7 (3).
    int jvalid[4], jdst[4], jtl[4], jmt[4];
#pragma unroll
    for (int s = 0; s < 4; ++s) {
        int j = (w <= 5) ? (w * 4 + s) : (24 + (w - 6) * 3 + s);
        int nj = (w <= 5) ? 4 : 3;
        jvalid[s] = (s < nj) && (j < 30);
        int mt = (j < 10) ? 0 : (j < 20) ? 2 : 1;
        int tl = (j < 20) ? (j % 10) : (j - 20);
        jmt[s] = mt; jtl[s] = tl;
        jdst[s] = mt * 1440 + tl * 16 * GMS;
    }

    // ---- stage matrices (f16, bias folded at k=52; w_lin folded at row 153 of mt1) ----
    half8 Wj[4][2];
#pragma unroll 1
    for (int mt = 0; mt < 3; ++mt) {
        const void* wm = (mt == 0) ? whh1 : (mt == 1) ? whh2 : wih2;
        for (int e = tid; e < 160 * 64; e += TPB) {
            int g = e >> 6, k = e & 63;
            float v = 0.0f;
            if (g < 3 * HH) {
                if (k < HH) v = loadf(wm, (size_t)g * HH + k, isbf);
                else if (k == 52) {
                    if (mt == 0)      v = loadf(bhh1, g, isbf) + ((g < 2 * HH) ? loadf(bih1, g, isbf) : 0.0f);
                    else if (mt == 1) v = loadf(bhh2, g, isbf);
                    else              v = loadf(bih2, g, isbf);
                }
            } else if (mt == 1 && g == 153) {
                // output projection row: C[153][b] = wl . h2[b] + blv
                if (k < HH) v = loadf(wlin, k, isbf);
                else if (k == 52) v = blv;
            }
            stg[e] = (_Float16)v;
        }
        __syncthreads();
#pragma unroll
        for (int s = 0; s < 4; ++s) {
            if (jvalid[s] && jmt[s] == mt) {
                Wj[s][0] = *(const half8*)(stg + (size_t)(16 * jtl[s] + n16) * 64 + quad * 8);
                Wj[s][1] = *(const half8*)(stg + (size_t)(16 * jtl[s] + n16) * 64 + 32 + quad * 8);
            }
        }
        __syncthreads();
    }

    // ---- init runtime LDS ----
    for (int e = tid; e < 1152; e += TPB) { h1b[e] = (_Float16)0; h2b[e] = (_Float16)0; }
    for (int e = tid; e < 3 * 160 * GMS; e += TPB) gbuf[e] = 0.0f;

    // x prefetch, double-buffered
    float xreg = 0.0f, xnext = 0.0f;
    if (lane < T) xreg = loadf(xg, (size_t)myb * T + lane, isbf);
    __syncthreads();
    if (tid < BPB) { h1b[tid * 72 + 52] = (_Float16)1.0f; h2b[tid * 72 + 52] = (_Float16)1.0f; }
    __syncthreads();

    // ---- prologue: gh1(0) from bias-slot h1 — mt0 jobs (live on waves 0-2) ----
    {
        half8 A0 = *(const half8*)(h1b + n16 * 72 + quad * 8);
        half8 A1 = *(const half8*)(h1b + n16 * 72 + 32 + quad * 8);
#pragma unroll
        for (int s = 0; s < 4; ++s) {
            if (jvalid[s] && jmt[s] == 0) {
                f4 acc = {0.f, 0.f, 0.f, 0.f};
                acc = MF(A0, Wj[s][0], acc); acc = MF(A1, Wj[s][1], acc);
                if (quad < 2) *(f4*)(gbuf + jdst[s] + n16 * GMS + quad * 4) = acc;
            }
        }
    }
    __syncthreads();

    float h1p = 0.0f, h2p = 0.0f;
    const int base1 = 160 * GMS, base2 = 320 * GMS;
    const int orow = base1 + 153 * GMS;   // folded output row
    // hoisted per-lane gbuf offsets (loop-invariant)
    const int o1r = il * GMS + w, o1z = (HH + il) * GMS + w, o1n = (2 * HH + il) * GMS + w;

    // ================= ENCODE loop: t = 0 .. T-1 (no feedback code, no t<T tests) =================
    for (int t = 0; t < T; ++t) {
        // ---- P1: e1(t) + e2(t-1), all waves, batch = w ----
        float g1r = gbuf[o1r], g1z = gbuf[o1z], g1n = gbuf[o1n];
        float xv = __builtin_bit_cast(float, __builtin_amdgcn_readlane(__builtin_bit_cast(int, xreg), t & 63));
        {
            float r = sigm(fmaf(xv, wr1, g1r));
            float z = sigm(fmaf(xv, wz1, g1z));
            float n = tanh_fast(fmaf(xv, wn1, bn1) + r * g1n);
            float h = n + z * (h1p - n); h1p = h;
            if (li) h1b[w * 72 + il] = (_Float16)h;
        }
        if (t > 0) {   // e2(t-1), off the e1 critical path
            float ghr = gbuf[base1 + o1r], ghz = gbuf[base1 + o1z], ghn = gbuf[base1 + o1n];
            float gir = gbuf[base2 + o1r], giz = gbuf[base2 + o1z], gin = gbuf[base2 + o1n];
            float r2 = sigm(gir + ghr), z2 = sigm(giz + ghz);
            float n2 = tanh_fast(gin + r2 * ghn);
            float h = n2 + z2 * (h2p - n2); h2p = h;
            if (li) h2b[w * 72 + il] = (_Float16)h;
        }
        // out(t-2) = wl . h2(t-2) + blv, produced by the mt1 matmul at step t-1
        if (lane == 0 && t >= 2)
            obufL[w * 36 + ((t - 2) & 31)] = gbuf[orow + w];
        LBAR();

        // ---- P2: each wave reads ONE A pair; <=4 tile-jobs each ----
        {
            const _Float16* ah = (w >= 5) ? h2b : h1b;
            half8 A0 = *(const half8*)(ah + n16 * 72 + quad * 8);
            half8 A1 = *(const half8*)(ah + n16 * 72 + 32 + quad * 8);
#pragma unroll
            for (int s = 0; s < 4; ++s) {
                if (jvalid[s]) {
                    f4 acc = {0.f, 0.f, 0.f, 0.f};
                    acc = MF(A0, Wj[s][0], acc); acc = MF(A1, Wj[s][1], acc);
                    if (quad < 2) *(f4*)(gbuf + jdst[s] + n16 * GMS + quad * 4) = acc;
                }
            }
        }
        // waves 6,7 flush the last 32 outputs of all 8 batches: [t-33 .. t-2]
        if (w >= 6 && (t & 31) == 1 && t > 32) {
            int fb = t - 33;
#pragma unroll
            for (int k2 = 0; k2 < 2; ++k2) {
                int et = ((w - 6) << 7) + (k2 << 6) + lane;   // 0..255
                int b = et >> 5, tt = et & 31;
                storef(dout, (size_t)(bg0 + b) * TF + fb + tt, obufL[b * 36 + tt], isbf);
            }
        }
        // x double-buffer: issue next window's load 63 steps early; swap at window end
        if ((t & 63) == 0) {
            int base = t + 64;
            if (base < T) {
                int src = base + lane;
                xnext = (src < T) ? loadf(xg, (size_t)myb * T + src, isbf) : 0.0f;
            }
        } else if ((t & 63) == 63) {
            xreg = xnext;
        }
        LBAR();
    }

    // ================= FEEDBACK loop: t = T .. TF-1 (serial e2 -> out -> e1; no x logic) =================
    for (int t = T; t < TF; ++t) {
        // ---- P1 ----
        float g1r = gbuf[o1r], g1z = gbuf[o1z], g1n = gbuf[o1n];
        if (t == T && lane == 0)   // patch the one output the folded row still owes (out(T-2))
            obufL[w * 36 + ((t - 2) & 31)] = gbuf[orow + w];
        {
            float ghr = gbuf[base1 + o1r], ghz = gbuf[base1 + o1z], ghn = gbuf[base1 + o1n];
            float gir = gbuf[base2 + o1r], giz = gbuf[base2 + o1z], gin = gbuf[base2 + o1n];
            float r2 = sigm(gir + ghr), z2 = sigm(giz + ghz);
            float n2 = tanh_fast(gin + r2 * ghn);
            float h = n2 + z2 * (h2p - n2); h2p = h;
            float p = 0.0f;
            if (li) {
                h2b[w * 72 + il] = (_Float16)h;
                p = h * wl;
            }
            float outv = wave_sum(p) + blv;
            if (lane == 0) obufL[w * 36 + ((t - 1) & 31)] = outv;
            float r = sigm(fmaf(outv, wr1, g1r));
            float z = sigm(fmaf(outv, wz1, g1z));
            float n = tanh_fast(fmaf(outv, wn1, bn1) + r * g1n);
            float h1 = n + z * (h1p - n); h1p = h1;
            if (li) h1b[w * 72 + il] = (_Float16)h1;
        }
        LBAR();
        // ---- P2 ----
        {
            const _Float16* ah = (w >= 5) ? h2b : h1b;
            half8 A0 = *(const half8*)(ah + n16 * 72 + quad * 8);
            half8 A1 = *(const half8*)(ah + n16 * 72 + 32 + quad * 8);
#pragma unroll
            for (int s = 0; s < 4; ++s) {
                if (jvalid[s]) {
                    f4 acc = {0.f, 0.f, 0.f, 0.f};
                    acc = MF(A0, Wj[s][0], acc); acc = MF(A1, Wj[s][1], acc);
                    if (quad < 2) *(f4*)(gbuf + jdst[s] + n16 * GMS + quad * 4) = acc;
                }
            }
        }
        if (w >= 6 && (t & 31) == 0) {   // flush [t-32 .. t-1]
            int fb = t - 32;
#pragma unroll
            for (int k2 = 0; k2 < 2; ++k2) {
                int et = ((w - 6) << 7) + (k2 << 6) + lane;   // 0..255
                int b = et >> 5, tt = et & 31;
                storef(dout, (size_t)(bg0 + b) * TF + fb + tt, obufL[b * 36 + tt], isbf);
            }
        }
        LBAR();
    }

    // ---- epilogue: e2(TF-1) + out(TF-1) + tail flush ----
    {
        float ghr = gbuf[base1 + o1r], ghz = gbuf[base1 + o1z], ghn = gbuf[base1 + o1n];
        float gir = gbuf[base2 + o1r], giz = gbuf[base2 + o1z], gin = gbuf[base2 + o1n];
        float p = 0.0f;
        float r2 = sigm(gir + ghr), z2 = sigm(giz + ghz);
        float n2 = tanh_fast(gin + r2 * ghn);
        float h = n2 + z2 * (h2p - n2);
        if (li) p = h * wl;
        float osum = wave_sum(p) + blv;
        if (lane == 0) obufL[w * 36 + ((TF - 1) & 31)] = osum;
    }
    __syncthreads();
    {
        int base = (TF - 1) & ~31, rem = TF - base;
        if (tid < BPB * 32) {
            int b = tid >> 5, tt = tid & 31;
            if (tt < rem)
                storef(dout, (size_t)(bg0 + b) * TF + base + tt, obufL[b * 36 + tt], isbf);
        }
    }
}

extern "C" void kernel_launch(void* const* d_in, const int* in_sizes, int n_in,
                              void* d_out, int out_size, void* d_ws, size_t ws_size,
                              hipStream_t stream) {
    const int B = 2048;
    const int T = in_sizes[0] / B;   // 1000
    const int TF = out_size / B;     // 2000
    gru_kernel<<<dim3(B / BPB), dim3(TPB), 0, stream>>>(
        d_in[0], d_in[1], d_in[2], d_in[3], d_in[4], d_in[5],
        d_in[6], d_in[7], d_in[8], d_in[9], d_in[10],
        d_out, T, TF);
}